// Round 10
// baseline (256.919 us; speedup 1.0000x reference)
//
#include <hip/hip_runtime.h>
#include <math.h>

#define CCH   256
#define NPIX  4096
#define BATCH 4

typedef __attribute__((ext_vector_type(8))) short    s16x8;
typedef __attribute__((ext_vector_type(4))) short    s16x4;
typedef __attribute__((ext_vector_type(8))) _Float16 f16x8;
typedef __attribute__((ext_vector_type(4))) float    f32x4;

__device__ __forceinline__ unsigned short f2bf(float f) {
    unsigned int u = __float_as_uint(f);
    u += 0x7fff + ((u >> 16) & 1);          // RNE; values are finite
    return (unsigned short)(u >> 16);
}
__device__ __forceinline__ float bf2f(unsigned short h) {
    return __uint_as_float(((unsigned int)h) << 16);
}
__device__ __forceinline__ unsigned short f2h(float f) {
    _Float16 h = (_Float16)f;               // v_cvt_f16_f32, RNE
    return *(unsigned short*)&h;
}
__device__ __forceinline__ float h2f(unsigned short u) {
    _Float16 h = *(_Float16*)&u;
    return (float)h;
}

// q/k frag (16x16x32 A/B layout), element for (pixel n, dim d):
//   tile = n>>4, lane = (d>>3)*16 + (n&15), elem = d&7
__device__ __forceinline__ size_t qk_addr(int b, int n, int d) {
    return ((((size_t)b * 256 + (n >> 4)) * 64 + ((d >> 3) << 4) + (n & 15)) << 3) + (d & 7);
}
// v frag: standard A-layout for PV; k = j (32-step), m = c (16-tile):
__device__ __forceinline__ size_t v_addr(int b, int j, int c) {
    return ((((((size_t)b * 64 + (j >> 6)) * 16 + (c >> 4)) * 2 + ((j >> 5) & 1)) * 64
            + (((j >> 3) & 3) << 4) + (c & 15)) << 3) + (j & 7);
}

// ---------------- W -> A-frag fp16 (hi/lo for q,k; hi for v), once ----------------
__global__ __launch_bounds__(64) void wcast_kernel(
    const float* __restrict__ Wq, const float* __restrict__ bq,
    const float* __restrict__ Wk, const float* __restrict__ bk,
    const float* __restrict__ Wv, const float* __restrict__ bv,
    unsigned short* __restrict__ wfh, unsigned short* __restrict__ wfl,
    float* __restrict__ bias_ws)
{
    const int rt = blockIdx.x;
    const int lane = threadIdx.x, l15 = lane & 15, quad = lane >> 4;
    const float *Ws, *bs; int roff; float scale = 1.0f;
    if (rt < 2)      { Ws = Wq; bs = bq; roff = rt * 16;      scale = 1.44269504f; }
    else if (rt < 4) { Ws = Wk; bs = bk; roff = (rt - 2) * 16; }
    else             { Ws = Wv; bs = bv; roff = (rt - 4) * 16; }

    const float* wrow = Ws + (size_t)(roff + l15) * CCH + quad * 8;
    for (int kb = 0; kb < 8; ++kb) {
        s16x8 h, l;
        #pragma unroll
        for (int d = 0; d < 8; ++d) {
            float wv = wrow[kb * 32 + d] * scale;
            unsigned short hh = f2h(wv);
            h[d] = (short)hh;
            l[d] = (short)f2h(wv - h2f(hh));
        }
        *(s16x8*)&wfh[(((size_t)rt * 8 + kb) * 64 + lane) * 8] = h;
        if (rt < 4) *(s16x8*)&wfl[(((size_t)rt * 8 + kb) * 64 + lane) * 8] = l;
    }
    if (lane < 16) bias_ws[rt * 16 + lane] = bs[roff + lane] * scale;
}

// ---------------- fused cast+projection (fp16 internal, spill-free; R9-verified) ----------------
__global__ __launch_bounds__(256, 4) void proj_kernel(
    const float* __restrict__ x,
    const unsigned short* __restrict__ wfh, const unsigned short* __restrict__ wfl,
    const float* __restrict__ bias_ws,
    unsigned short* __restrict__ q_hi, unsigned short* __restrict__ k_hi,
    unsigned short* __restrict__ v_frag)
{
    const int t = threadIdx.x;
    const int rh = t >> 6, lane = t & 63, l15 = lane & 15, quad = lane >> 4;
    const int b = blockIdx.y;
    const int nt = blockIdx.x;

    const float* xb = x + (size_t)b * CCH * NPIX + nt * 16 + l15;

    f32x4 aq0 = {0.f, 0.f, 0.f, 0.f};
    f32x4 aq1 = {0.f, 0.f, 0.f, 0.f};
    f32x4 av[4];
    #pragma unroll
    for (int i = 0; i < 4; ++i) av[i] = (f32x4){0.f, 0.f, 0.f, 0.f};

    #pragma unroll 2
    for (int kb = 0; kb < 8; ++kb) {
        f16x8 xh, xl;
        #pragma unroll
        for (int d = 0; d < 8; ++d) {
            float xv = xb[(size_t)(kb * 32 + quad * 8 + d) * NPIX];
            _Float16 hh = (_Float16)xv;
            xh[d] = hh;
            xl[d] = (_Float16)(xv - (float)hh);
        }
        {
            const f16x8 ah = *(const f16x8*)&wfh[(((size_t)rh * 8 + kb) * 64 + lane) * 8];
            const f16x8 al = *(const f16x8*)&wfl[(((size_t)rh * 8 + kb) * 64 + lane) * 8];
            aq0 = __builtin_amdgcn_mfma_f32_16x16x32_f16(ah, xh, aq0, 0, 0, 0);
            aq1 = __builtin_amdgcn_mfma_f32_16x16x32_f16(ah, xl, aq1, 0, 0, 0);
            aq1 = __builtin_amdgcn_mfma_f32_16x16x32_f16(al, xh, aq1, 0, 0, 0);
        }
        #pragma unroll
        for (int i = 0; i < 4; ++i) {
            const int rt = 4 + rh * 4 + i;
            const f16x8 ah = *(const f16x8*)&wfh[(((size_t)rt * 8 + kb) * 64 + lane) * 8];
            av[i] = __builtin_amdgcn_mfma_f32_16x16x32_f16(ah, xh, av[i], 0, 0, 0);
        }
    }

    const int n = nt * 16 + l15;
    {
        s16x4 h4;
        #pragma unroll
        for (int rr = 0; rr < 4; ++rr) {
            const int rloc = quad * 4 + rr;
            const float val = aq0[rr] + aq1[rr] + bias_ws[rh * 16 + rloc];
            h4[rr] = (short)f2h(val);
        }
        if (rh < 2) {
            const size_t a = qk_addr(b, n, rh * 16 + quad * 4);
            *(s16x4*)&q_hi[a] = h4;
        } else {
            const size_t a = qk_addr(b, n, (rh - 2) * 16 + quad * 4);
            *(s16x4*)&k_hi[a] = h4;
        }
    }
    #pragma unroll
    for (int i = 0; i < 4; ++i) {
        const int vt = rh * 4 + i;
        #pragma unroll
        for (int rr = 0; rr < 4; ++rr) {
            const int rloc = quad * 4 + rr;
            const float val = av[i][rr] + bias_ws[(4 + vt) * 16 + rloc];
            v_frag[v_addr(b, n, vt * 16 + rloc)] = f2bf(val);
        }
    }
}

// ---------------- flash attention: 2-step windows, 4-buffer P rotation ----------------
// 512 blocks (2/CU) x 8 waves = (jh 0..1, ch 0..3).  fp16 QK (2 MFMAs/step).
// CHANGE vs the 56.0us version: each barrier window now processes TWO j-steps.
// P buf for step t = t&3; even windows read bufs (0,1) & write (2,3), odd
// windows swap.  One lgkm-barrier per window -> 16 barriers instead of 32,
// and each region holds 2 independent QK chains + 32 independent PV MFMAs.
// Register discipline: only vA0-3 live across the barrier (~112 VGPR peak).
#define BARRIER_LGKM() do { \
    asm volatile("s_waitcnt lgkmcnt(0)" ::: "memory"); \
    __builtin_amdgcn_s_barrier(); \
    asm volatile("" ::: "memory"); \
} while (0)

#define QK_STEP(KF, BUFC) do { \
    f32x4 a0 = __builtin_amdgcn_mfma_f32_16x16x32_f16((KF), qf0, (f32x4){0.f,0.f,0.f,0.f}, 0, 0, 0); \
    f32x4 a1 = __builtin_amdgcn_mfma_f32_16x16x32_f16((KF), qf1, (f32x4){0.f,0.f,0.f,0.f}, 0, 0, 0); \
    unsigned int u0 = __float_as_uint(__builtin_exp2f(a0[0])) + 0x8000u; \
    unsigned int u1 = __float_as_uint(__builtin_exp2f(a0[1])) + 0x8000u; \
    unsigned int u2 = __float_as_uint(__builtin_exp2f(a0[2])) + 0x8000u; \
    unsigned int u3 = __float_as_uint(__builtin_exp2f(a0[3])) + 0x8000u; \
    uint2 pv; \
    pv.x = __builtin_amdgcn_perm(u1, u0, 0x07060302u); \
    pv.y = __builtin_amdgcn_perm(u3, u2, 0x07060302u); \
    *(uint2*)&p_lds[jh][BUFC][0 * 2 + pfrag_jj][(prow * 16 + l15) * 8 + pcol] = pv; \
    u0 = __float_as_uint(__builtin_exp2f(a1[0])) + 0x8000u; \
    u1 = __float_as_uint(__builtin_exp2f(a1[1])) + 0x8000u; \
    u2 = __float_as_uint(__builtin_exp2f(a1[2])) + 0x8000u; \
    u3 = __float_as_uint(__builtin_exp2f(a1[3])) + 0x8000u; \
    uint2 pw; \
    pw.x = __builtin_amdgcn_perm(u1, u0, 0x07060302u); \
    pw.y = __builtin_amdgcn_perm(u3, u2, 0x07060302u); \
    *(uint2*)&p_lds[jh][BUFC][1 * 2 + pfrag_jj][(prow * 16 + l15) * 8 + pcol] = pw; \
} while (0)

#define PV8(VA, VB, PA, PB, PC, PD, I0, I1) do { \
    acc[I0] = __builtin_amdgcn_mfma_f32_16x16x32_bf16((VA), (PA), acc[I0], 0, 0, 0); \
    acc[I0] = __builtin_amdgcn_mfma_f32_16x16x32_bf16((VB), (PB), acc[I0], 0, 0, 0); \
    acc[I1] = __builtin_amdgcn_mfma_f32_16x16x32_bf16((VA), (PC), acc[I1], 0, 0, 0); \
    acc[I1] = __builtin_amdgcn_mfma_f32_16x16x32_bf16((VB), (PD), acc[I1], 0, 0, 0); \
} while (0)

// One 2-step window.  T: first j-step (even); reads P bufs BR0,BR1; QK for
// steps T+2,T+3 into bufs BW0,BW1 using KU0,KU1; prefetches K(T+4),K(T+5)
// into KL0,KL1.  DO_QK guards the tail.
#define ATTN_WIN(T, BR0, BR1, BW0, BW1, KU0, KU1, KL0, KL1, DO_QK) do { \
    const int jtA = jh * 32 + (T); \
    /* P reads for both steps -- hidden under QK x2 */ \
    const s16x8 pfA0 = *(const s16x8*)&p_lds[jh][BR0][0][lane * 8]; \
    const s16x8 pfA1 = *(const s16x8*)&p_lds[jh][BR0][1][lane * 8]; \
    const s16x8 pfA2 = *(const s16x8*)&p_lds[jh][BR0][2][lane * 8]; \
    const s16x8 pfA3 = *(const s16x8*)&p_lds[jh][BR0][3][lane * 8]; \
    const s16x8 pfB0 = *(const s16x8*)&p_lds[jh][BR1][0][lane * 8]; \
    const s16x8 pfB1 = *(const s16x8*)&p_lds[jh][BR1][1][lane * 8]; \
    const s16x8 pfB2 = *(const s16x8*)&p_lds[jh][BR1][2][lane * 8]; \
    const s16x8 pfB3 = *(const s16x8*)&p_lds[jh][BR1][3][lane * 8]; \
    const size_t vbaseA = (((size_t)jtA * 16 + ch * 4) * 2) * 512; \
    const size_t vbaseB = vbaseA + 16384;  /* (jtA+1)*16*2*512 */ \
    /* step-A first-half V: long cover, only these live across the barrier */ \
    const s16x8 vA0 = *(const s16x8*)(vb + vbaseA); \
    const s16x8 vA1 = *(const s16x8*)(vb + vbaseA + 512); \
    const s16x8 vA2 = *(const s16x8*)(vb + vbaseA + 1024); \
    const s16x8 vA3 = *(const s16x8*)(vb + vbaseA + 1536); \
    if (DO_QK) { QK_STEP(KU0, BW0); QK_STEP(KU1, BW1); } \
    { \
        const int tp0 = ((T) + 4 < 32) ? (T) + 4 : 0; \
        const int tp1 = ((T) + 5 < 32) ? (T) + 5 : 0; \
        KL0 = *(const f16x8*)(khb + (size_t)((jh * 32 + tp0) * 4 + ch) * 512); \
        KL1 = *(const f16x8*)(khb + (size_t)((jh * 32 + tp1) * 4 + ch) * 512); \
    } \
    /* denominator partials: ch0 -> it0 frags, ch1 -> it1 frags, both steps */ \
    if (ch == 0) { \
        lacc = __builtin_amdgcn_mfma_f32_16x16x32_bf16(ones, pfA0, lacc, 0, 0, 0); \
        lacc = __builtin_amdgcn_mfma_f32_16x16x32_bf16(ones, pfA1, lacc, 0, 0, 0); \
        lacc = __builtin_amdgcn_mfma_f32_16x16x32_bf16(ones, pfB0, lacc, 0, 0, 0); \
        lacc = __builtin_amdgcn_mfma_f32_16x16x32_bf16(ones, pfB1, lacc, 0, 0, 0); \
    } else if (ch == 1) { \
        lacc = __builtin_amdgcn_mfma_f32_16x16x32_bf16(ones, pfA2, lacc, 0, 0, 0); \
        lacc = __builtin_amdgcn_mfma_f32_16x16x32_bf16(ones, pfA3, lacc, 0, 0, 0); \
        lacc = __builtin_amdgcn_mfma_f32_16x16x32_bf16(ones, pfB2, lacc, 0, 0, 0); \
        lacc = __builtin_amdgcn_mfma_f32_16x16x32_bf16(ones, pfB3, lacc, 0, 0, 0); \
    } \
    BARRIER_LGKM(); \
    /* remaining V: issue all, consumed >=8 MFMAs later each */ \
    const s16x8 vA4 = *(const s16x8*)(vb + vbaseA + 2048); \
    const s16x8 vA5 = *(const s16x8*)(vb + vbaseA + 2560); \
    const s16x8 vA6 = *(const s16x8*)(vb + vbaseA + 3072); \
    const s16x8 vA7 = *(const s16x8*)(vb + vbaseA + 3584); \
    const s16x8 vB0 = *(const s16x8*)(vb + vbaseB); \
    const s16x8 vB1 = *(const s16x8*)(vb + vbaseB + 512); \
    const s16x8 vB2 = *(const s16x8*)(vb + vbaseB + 1024); \
    const s16x8 vB3 = *(const s16x8*)(vb + vbaseB + 1536); \
    const s16x8 vB4 = *(const s16x8*)(vb + vbaseB + 2048); \
    const s16x8 vB5 = *(const s16x8*)(vb + vbaseB + 2560); \
    const s16x8 vB6 = *(const s16x8*)(vb + vbaseB + 3072); \
    const s16x8 vB7 = *(const s16x8*)(vb + vbaseB + 3584); \
    __builtin_amdgcn_s_setprio(1); \
    PV8(vA0, vA1, pfA0, pfA1, pfA2, pfA3, 0, 1); \
    PV8(vA2, vA3, pfA0, pfA1, pfA2, pfA3, 2, 3); \
    PV8(vA4, vA5, pfA0, pfA1, pfA2, pfA3, 4, 5); \
    PV8(vA6, vA7, pfA0, pfA1, pfA2, pfA3, 6, 7); \
    PV8(vB0, vB1, pfB0, pfB1, pfB2, pfB3, 0, 1); \
    PV8(vB2, vB3, pfB0, pfB1, pfB2, pfB3, 2, 3); \
    PV8(vB4, vB5, pfB0, pfB1, pfB2, pfB3, 4, 5); \
    PV8(vB6, vB7, pfB0, pfB1, pfB2, pfB3, 6, 7); \
    __builtin_amdgcn_s_setprio(0); \
} while (0)

__global__ __launch_bounds__(512, 4) void attn_kernel(
    const unsigned short* __restrict__ q_hi,
    const unsigned short* __restrict__ k_hi,
    const unsigned short* __restrict__ v_frag,
    const float* __restrict__ x, float* __restrict__ out)
{
    __shared__ unsigned short p_lds[2][4][4][512];   // [jh][buf][frag][lane*8] = 32 KB
    __shared__ f32x4 comb[2][4][4][64];              // [jh_src][ch][ct][lane] = 32 KB
    __shared__ float lds_l[2][2][16];

    const int t = threadIdx.x;
    const int w = t >> 6, lane = t & 63, l15 = lane & 15, quad = lane >> 4;
    const int jh = w >> 2, ch = w & 3;

    const int f = blockIdx.x;                 // 0..511; XCD-pair per batch
    const int xcd = f & 7;
    const int b = xcd >> 1;
    const int ib = ((xcd & 1) << 6) + (f >> 3);   // i-block 0..127 (32 pixels)

    f16x8 qf0, qf1;
    {
        const size_t qo0 = ((size_t)b * 256 + ib * 2 + 0) * 512 + (size_t)lane * 8;
        const size_t qo1 = ((size_t)b * 256 + ib * 2 + 1) * 512 + (size_t)lane * 8;
        qf0 = *(const f16x8*)(q_hi + qo0);
        qf1 = *(const f16x8*)(q_hi + qo1);
    }

    const s16x8 ones = { (short)0x3F80, (short)0x3F80, (short)0x3F80, (short)0x3F80,
                         (short)0x3F80, (short)0x3F80, (short)0x3F80, (short)0x3F80 };

    f32x4 acc[8];                             // [ct*2+it], constant indices only
    #pragma unroll
    for (int i = 0; i < 8; ++i) acc[i] = (f32x4){0.f, 0.f, 0.f, 0.f};
    f32x4 lacc = {0.f, 0.f, 0.f, 0.f};

    const unsigned short* khb = k_hi + (size_t)b * 131072 + (size_t)lane * 8;
    const unsigned short* vb  = v_frag + (size_t)b * 1048576 + (size_t)lane * 8;

    const int prow = ((ch & 1) << 1) + (quad >> 1);
    const int pcol = ((quad & 1) << 2);
    const int pfrag_jj = ch >> 1;

    // ---- prologue: QK(0)->buf0, QK(1)->buf1; then ka,kb = K(2),K(3) ----
    f16x8 ka, kb, kc, kd;
    ka = *(const f16x8*)(khb + (size_t)((jh * 32 + 0) * 4 + ch) * 512);
    kb = *(const f16x8*)(khb + (size_t)((jh * 32 + 1) * 4 + ch) * 512);
    QK_STEP(ka, 0);
    QK_STEP(kb, 1);
    ka = *(const f16x8*)(khb + (size_t)((jh * 32 + 2) * 4 + ch) * 512);
    kb = *(const f16x8*)(khb + (size_t)((jh * 32 + 3) * 4 + ch) * 512);
    BARRIER_LGKM();

    #pragma unroll 1
    for (int w2 = 0; w2 < 8; ++w2) {
        ATTN_WIN(4 * w2,     0, 1, 2, 3, ka, kb, kc, kd, 1);
        ATTN_WIN(4 * w2 + 2, 2, 3, 0, 1, kc, kd, ka, kb, (w2 < 7));
    }

    // ---- epilogue (constant indices inside wave-uniform branches) ----
    if (ch < 2 && lane < 16) lds_l[jh][ch][lane] = lacc[0];
    if (jh == 0) {          // own it0; publish it1
        #pragma unroll
        for (int ct = 0; ct < 4; ++ct)
            comb[0][ch][ct][lane] = acc[ct * 2 + 1];
    } else {                // own it1; publish it0
        #pragma unroll
        for (int ct = 0; ct < 4; ++ct)
            comb[1][ch][ct][lane] = acc[ct * 2 + 0];
    }
    __syncthreads();
    const float linv = 1.f / (lds_l[0][jh][l15] + lds_l[1][jh][l15]);
    const int ibase = (ib * 2 + jh) * 16 + l15;
    #pragma unroll
    for (int ct = 0; ct < 4; ++ct) {
        f32x4 a;
        if (jh == 0) a = acc[ct * 2 + 0];
        else         a = acc[ct * 2 + 1];
        a += comb[1 - jh][ch][ct][lane];
        #pragma unroll
        for (int rr = 0; rr < 4; ++rr) {
            const int c = ch * 64 + ct * 16 + quad * 4 + rr;
            const size_t idx = ((size_t)b * CCH + c) * NPIX + ibase;
            out[idx] = a[rr] * linv + x[idx];
        }
    }
}

extern "C" void kernel_launch(void* const* d_in, const int* in_sizes, int n_in,
                              void* d_out, int out_size, void* d_ws, size_t ws_size,
                              hipStream_t stream) {
    const float* x  = (const float*)d_in[0];
    const float* Wq = (const float*)d_in[1];
    const float* bq = (const float*)d_in[2];
    const float* Wk = (const float*)d_in[3];
    const float* bk = (const float*)d_in[4];
    const float* Wv = (const float*)d_in[5];
    const float* bv = (const float*)d_in[6];
    float* out = (float*)d_out;

    unsigned short* ws = (unsigned short*)d_ws;
    unsigned short* q_hi   = ws;                 //   524,288 (fp16)
    unsigned short* k_hi   = ws + 1048576;       //   524,288 (fp16)
    unsigned short* v_frag = ws + 2097152;       // 4,194,304 (bf16)
    unsigned short* wfh    = ws + 6291456;       //    81,920 (fp16)
    unsigned short* wfl    = ws + 6373376;       //    16,384 (fp16)
    float*          bias_ws = (float*)(ws + 6389760);  // 320 floats

    wcast_kernel<<<20, 64, 0, stream>>>(Wq, bq, Wk, bk, Wv, bv, wfh, wfl, bias_ws);
    proj_kernel<<<dim3(256, BATCH), 256, 0, stream>>>(x, wfh, wfl, bias_ws,
                                                      q_hi, k_hi, v_frag);
    attn_kernel<<<512, 512, 0, stream>>>(q_hi, k_hi, v_frag, x, out);
}

// Round 12
// 145.225 us; speedup vs baseline: 1.7691x; 1.7691x over previous
//
#include <hip/hip_runtime.h>
#include <math.h>

#define CCH   256
#define NPIX  4096
#define BATCH 4

typedef __attribute__((ext_vector_type(8))) short    s16x8;
typedef __attribute__((ext_vector_type(4))) short    s16x4;
typedef __attribute__((ext_vector_type(8))) _Float16 f16x8;
typedef __attribute__((ext_vector_type(4))) float    f32x4;

__device__ __forceinline__ unsigned short f2bf(float f) {
    unsigned int u = __float_as_uint(f);
    u += 0x7fff + ((u >> 16) & 1);          // RNE; values are finite
    return (unsigned short)(u >> 16);
}
__device__ __forceinline__ float bf2f(unsigned short h) {
    return __uint_as_float(((unsigned int)h) << 16);
}
__device__ __forceinline__ unsigned short f2h(float f) {
    _Float16 h = (_Float16)f;               // v_cvt_f16_f32, RNE
    return *(unsigned short*)&h;
}
__device__ __forceinline__ float h2f(unsigned short u) {
    _Float16 h = *(_Float16*)&u;
    return (float)h;
}

// q/k frag (16x16x32 A/B layout), element for (pixel n, dim d):
//   tile = n>>4, lane = (d>>3)*16 + (n&15), elem = d&7
__device__ __forceinline__ size_t qk_addr(int b, int n, int d) {
    return ((((size_t)b * 256 + (n >> 4)) * 64 + ((d >> 3) << 4) + (n & 15)) << 3) + (d & 7);
}
// v frag: standard A-layout for PV; k = j (32-step), m = c (16-tile):
__device__ __forceinline__ size_t v_addr(int b, int j, int c) {
    return ((((((size_t)b * 64 + (j >> 6)) * 16 + (c >> 4)) * 2 + ((j >> 5) & 1)) * 64
            + (((j >> 3) & 3) << 4) + (c & 15)) << 3) + (j & 7);
}

// ---------------- W -> A-frag fp16 (hi/lo for q,k; hi for v), once ----------------
__global__ __launch_bounds__(64) void wcast_kernel(
    const float* __restrict__ Wq, const float* __restrict__ bq,
    const float* __restrict__ Wk, const float* __restrict__ bk,
    const float* __restrict__ Wv, const float* __restrict__ bv,
    unsigned short* __restrict__ wfh, unsigned short* __restrict__ wfl,
    float* __restrict__ bias_ws)
{
    const int rt = blockIdx.x;
    const int lane = threadIdx.x, l15 = lane & 15, quad = lane >> 4;
    const float *Ws, *bs; int roff; float scale = 1.0f;
    if (rt < 2)      { Ws = Wq; bs = bq; roff = rt * 16;      scale = 1.44269504f; }
    else if (rt < 4) { Ws = Wk; bs = bk; roff = (rt - 2) * 16; }
    else             { Ws = Wv; bs = bv; roff = (rt - 4) * 16; }

    const float* wrow = Ws + (size_t)(roff + l15) * CCH + quad * 8;
    for (int kb = 0; kb < 8; ++kb) {
        s16x8 h, l;
        #pragma unroll
        for (int d = 0; d < 8; ++d) {
            float wv = wrow[kb * 32 + d] * scale;
            unsigned short hh = f2h(wv);
            h[d] = (short)hh;
            l[d] = (short)f2h(wv - h2f(hh));
        }
        *(s16x8*)&wfh[(((size_t)rt * 8 + kb) * 64 + lane) * 8] = h;
        if (rt < 4) *(s16x8*)&wfl[(((size_t)rt * 8 + kb) * 64 + lane) * 8] = l;
    }
    if (lane < 16) bias_ws[rt * 16 + lane] = bs[roff + lane] * scale;
}

// ---------------- fused cast+projection (LDS-staged x, fp16 internal) ----------------
// CHANGE vs R9: x was read as 64 scalar dwords/thread at stride 16KB
// (column-major walk, latency-bound).  Now the block cooperatively stages its
// x-tile [256 rows x 16 cols] via 4 coalesced float4 loads/thread into a
// TRANSPOSED padded LDS buffer xs[col][row]; the kb-loop then reads two
// 16B-aligned float4 from LDS per kb.  Arithmetic is value-identical to R9.
__global__ __launch_bounds__(256, 4) void proj_kernel(
    const float* __restrict__ x,
    const unsigned short* __restrict__ wfh, const unsigned short* __restrict__ wfl,
    const float* __restrict__ bias_ws,
    unsigned short* __restrict__ q_hi, unsigned short* __restrict__ k_hi,
    unsigned short* __restrict__ v_frag)
{
    __shared__ float xs[16][260];   // [col 0..15][row 0..255], +4 pad vs 256

    const int t = threadIdx.x;
    const int rh = t >> 6, lane = t & 63, l15 = lane & 15, quad = lane >> 4;
    const int b = blockIdx.y;
    const int nt = blockIdx.x;

    // ---- cooperative stage: x[b][r][nt*16 + c] -> xs[c][r] ----
    {
        const float* xrow = x + (size_t)b * CCH * NPIX + nt * 16;
        #pragma unroll
        for (int i = 0; i < 4; ++i) {
            const int r  = i * 64 + (t >> 2);
            const int c4 = (t & 3) * 4;
            const float4 v = *(const float4*)&xrow[(size_t)r * NPIX + c4];
            xs[c4 + 0][r] = v.x;
            xs[c4 + 1][r] = v.y;
            xs[c4 + 2][r] = v.z;
            xs[c4 + 3][r] = v.w;
        }
    }
    __syncthreads();

    f32x4 aq0 = {0.f, 0.f, 0.f, 0.f};
    f32x4 aq1 = {0.f, 0.f, 0.f, 0.f};
    f32x4 av[4];
    #pragma unroll
    for (int i = 0; i < 4; ++i) av[i] = (f32x4){0.f, 0.f, 0.f, 0.f};

    #pragma unroll 2
    for (int kb = 0; kb < 8; ++kb) {
        const float4 xv0 = *(const float4*)&xs[l15][kb * 32 + quad * 8];
        const float4 xv1 = *(const float4*)&xs[l15][kb * 32 + quad * 8 + 4];
        const float xa[8] = { xv0.x, xv0.y, xv0.z, xv0.w,
                              xv1.x, xv1.y, xv1.z, xv1.w };
        f16x8 xh, xl;
        #pragma unroll
        for (int d = 0; d < 8; ++d) {
            const float xv = xa[d];
            _Float16 hh = (_Float16)xv;
            xh[d] = hh;
            xl[d] = (_Float16)(xv - (float)hh);
        }
        {
            const f16x8 ah = *(const f16x8*)&wfh[(((size_t)rh * 8 + kb) * 64 + lane) * 8];
            const f16x8 al = *(const f16x8*)&wfl[(((size_t)rh * 8 + kb) * 64 + lane) * 8];
            aq0 = __builtin_amdgcn_mfma_f32_16x16x32_f16(ah, xh, aq0, 0, 0, 0);
            aq1 = __builtin_amdgcn_mfma_f32_16x16x32_f16(ah, xl, aq1, 0, 0, 0);
            aq1 = __builtin_amdgcn_mfma_f32_16x16x32_f16(al, xh, aq1, 0, 0, 0);
        }
        #pragma unroll
        for (int i = 0; i < 4; ++i) {
            const int rt = 4 + rh * 4 + i;
            const f16x8 ah = *(const f16x8*)&wfh[(((size_t)rt * 8 + kb) * 64 + lane) * 8];
            av[i] = __builtin_amdgcn_mfma_f32_16x16x32_f16(ah, xh, av[i], 0, 0, 0);
        }
    }

    const int n = nt * 16 + l15;
    {
        s16x4 h4;
        #pragma unroll
        for (int rr = 0; rr < 4; ++rr) {
            const int rloc = quad * 4 + rr;
            const float val = aq0[rr] + aq1[rr] + bias_ws[rh * 16 + rloc];
            h4[rr] = (short)f2h(val);
        }
        if (rh < 2) {
            const size_t a = qk_addr(b, n, rh * 16 + quad * 4);
            *(s16x4*)&q_hi[a] = h4;
        } else {
            const size_t a = qk_addr(b, n, (rh - 2) * 16 + quad * 4);
            *(s16x4*)&k_hi[a] = h4;
        }
    }
    #pragma unroll
    for (int i = 0; i < 4; ++i) {
        const int vt = rh * 4 + i;
        #pragma unroll
        for (int rr = 0; rr < 4; ++rr) {
            const int rloc = quad * 4 + rr;
            const float val = av[i][rr] + bias_ws[(4 + vt) * 16 + rloc];
            v_frag[v_addr(b, n, vt * 16 + rloc)] = f2bf(val);
        }
    }
}

// ---------------- flash attention: R9-VERIFIED (56.0 us) -- byte-identical ----------------
// 512 blocks (2/CU) x 8 waves = (jh 0..1, ch 0..3).  fp16 QK (2 MFMAs/step);
// P bf16 (P = 2^s overflows fp16); 1 lgkm-barrier per j-step; V loads in
// flight across the barrier; PV under setprio(1).
#define BARRIER_LGKM() do { \
    asm volatile("s_waitcnt lgkmcnt(0)" ::: "memory"); \
    __builtin_amdgcn_s_barrier(); \
    asm volatile("" ::: "memory"); \
} while (0)

#define QK_STEP(KF, BUFC) do { \
    f32x4 a0 = __builtin_amdgcn_mfma_f32_16x16x32_f16((KF), qf0, (f32x4){0.f,0.f,0.f,0.f}, 0, 0, 0); \
    f32x4 a1 = __builtin_amdgcn_mfma_f32_16x16x32_f16((KF), qf1, (f32x4){0.f,0.f,0.f,0.f}, 0, 0, 0); \
    unsigned int u0 = __float_as_uint(__builtin_exp2f(a0[0])) + 0x8000u; \
    unsigned int u1 = __float_as_uint(__builtin_exp2f(a0[1])) + 0x8000u; \
    unsigned int u2 = __float_as_uint(__builtin_exp2f(a0[2])) + 0x8000u; \
    unsigned int u3 = __float_as_uint(__builtin_exp2f(a0[3])) + 0x8000u; \
    uint2 pv; \
    pv.x = __builtin_amdgcn_perm(u1, u0, 0x07060302u); \
    pv.y = __builtin_amdgcn_perm(u3, u2, 0x07060302u); \
    *(uint2*)&p_lds[jh][BUFC][0 * 2 + pfrag_jj][(prow * 16 + l15) * 8 + pcol] = pv; \
    u0 = __float_as_uint(__builtin_exp2f(a1[0])) + 0x8000u; \
    u1 = __float_as_uint(__builtin_exp2f(a1[1])) + 0x8000u; \
    u2 = __float_as_uint(__builtin_exp2f(a1[2])) + 0x8000u; \
    u3 = __float_as_uint(__builtin_exp2f(a1[3])) + 0x8000u; \
    uint2 pw; \
    pw.x = __builtin_amdgcn_perm(u1, u0, 0x07060302u); \
    pw.y = __builtin_amdgcn_perm(u3, u2, 0x07060302u); \
    *(uint2*)&p_lds[jh][BUFC][1 * 2 + pfrag_jj][(prow * 16 + l15) * 8 + pcol] = pw; \
} while (0)

#define ATTN_BODY(T, BUFC, KU, KL, DO_QK) do { \
    const int jt = jh * 32 + (T); \
    const s16x8 pf0 = *(const s16x8*)&p_lds[jh][BUFC][0][lane * 8]; \
    const s16x8 pf1 = *(const s16x8*)&p_lds[jh][BUFC][1][lane * 8]; \
    const s16x8 pf2 = *(const s16x8*)&p_lds[jh][BUFC][2][lane * 8]; \
    const s16x8 pf3 = *(const s16x8*)&p_lds[jh][BUFC][3][lane * 8]; \
    const size_t vbase = (((size_t)jt * 16 + ch * 4) * 2) * 512; \
    const s16x8 v0 = *(const s16x8*)(vb + vbase); \
    const s16x8 v1 = *(const s16x8*)(vb + vbase + 512); \
    const s16x8 v2 = *(const s16x8*)(vb + vbase + 1024); \
    const s16x8 v3 = *(const s16x8*)(vb + vbase + 1536); \
    if (DO_QK) { QK_STEP(KU, (BUFC) ^ 1); } \
    { \
        const int tpp = ((T) + 2 < 32) ? (T) + 2 : 0; \
        const size_t koff = (size_t)((jh * 32 + tpp) * 4 + ch) * 512; \
        KL = *(const f16x8*)(khb + koff); \
    } \
    if (ch == 0) { \
        lacc = __builtin_amdgcn_mfma_f32_16x16x32_bf16(ones, pf0, lacc, 0, 0, 0); \
        lacc = __builtin_amdgcn_mfma_f32_16x16x32_bf16(ones, pf1, lacc, 0, 0, 0); \
    } else if (ch == 1) { \
        lacc = __builtin_amdgcn_mfma_f32_16x16x32_bf16(ones, pf2, lacc, 0, 0, 0); \
        lacc = __builtin_amdgcn_mfma_f32_16x16x32_bf16(ones, pf3, lacc, 0, 0, 0); \
    } \
    BARRIER_LGKM(); \
    const s16x8 v4 = *(const s16x8*)(vb + vbase + 2048); \
    const s16x8 v5 = *(const s16x8*)(vb + vbase + 2560); \
    const s16x8 v6 = *(const s16x8*)(vb + vbase + 3072); \
    const s16x8 v7 = *(const s16x8*)(vb + vbase + 3584); \
    __builtin_amdgcn_s_setprio(1); \
    acc[0] = __builtin_amdgcn_mfma_f32_16x16x32_bf16(v0, pf0, acc[0], 0, 0, 0); \
    acc[0] = __builtin_amdgcn_mfma_f32_16x16x32_bf16(v1, pf1, acc[0], 0, 0, 0); \
    acc[1] = __builtin_amdgcn_mfma_f32_16x16x32_bf16(v0, pf2, acc[1], 0, 0, 0); \
    acc[1] = __builtin_amdgcn_mfma_f32_16x16x32_bf16(v1, pf3, acc[1], 0, 0, 0); \
    acc[2] = __builtin_amdgcn_mfma_f32_16x16x32_bf16(v2, pf0, acc[2], 0, 0, 0); \
    acc[2] = __builtin_amdgcn_mfma_f32_16x16x32_bf16(v3, pf1, acc[2], 0, 0, 0); \
    acc[3] = __builtin_amdgcn_mfma_f32_16x16x32_bf16(v2, pf2, acc[3], 0, 0, 0); \
    acc[3] = __builtin_amdgcn_mfma_f32_16x16x32_bf16(v3, pf3, acc[3], 0, 0, 0); \
    acc[4] = __builtin_amdgcn_mfma_f32_16x16x32_bf16(v4, pf0, acc[4], 0, 0, 0); \
    acc[4] = __builtin_amdgcn_mfma_f32_16x16x32_bf16(v5, pf1, acc[4], 0, 0, 0); \
    acc[5] = __builtin_amdgcn_mfma_f32_16x16x32_bf16(v4, pf2, acc[5], 0, 0, 0); \
    acc[5] = __builtin_amdgcn_mfma_f32_16x16x32_bf16(v5, pf3, acc[5], 0, 0, 0); \
    acc[6] = __builtin_amdgcn_mfma_f32_16x16x32_bf16(v6, pf0, acc[6], 0, 0, 0); \
    acc[6] = __builtin_amdgcn_mfma_f32_16x16x32_bf16(v7, pf1, acc[6], 0, 0, 0); \
    acc[7] = __builtin_amdgcn_mfma_f32_16x16x32_bf16(v6, pf2, acc[7], 0, 0, 0); \
    acc[7] = __builtin_amdgcn_mfma_f32_16x16x32_bf16(v7, pf3, acc[7], 0, 0, 0); \
    __builtin_amdgcn_s_setprio(0); \
} while (0)

__global__ __launch_bounds__(512, 4) void attn_kernel(
    const unsigned short* __restrict__ q_hi,
    const unsigned short* __restrict__ k_hi,
    const unsigned short* __restrict__ v_frag,
    const float* __restrict__ x, float* __restrict__ out)
{
    __shared__ unsigned short p_lds[2][2][4][512];   // [jh][dbuf][frag][lane*8] = 16 KB
    __shared__ f32x4 comb[2][4][4][64];              // [jh_src][ch][ct][lane] = 32 KB
    __shared__ float lds_l[2][2][16];

    const int t = threadIdx.x;
    const int w = t >> 6, lane = t & 63, l15 = lane & 15, quad = lane >> 4;
    const int jh = w >> 2, ch = w & 3;

    const int f = blockIdx.x;                 // 0..511; XCD-pair per batch
    const int xcd = f & 7;
    const int b = xcd >> 1;
    const int ib = ((xcd & 1) << 6) + (f >> 3);   // i-block 0..127 (32 pixels)

    f16x8 qf0, qf1;
    {
        const size_t qo0 = ((size_t)b * 256 + ib * 2 + 0) * 512 + (size_t)lane * 8;
        const size_t qo1 = ((size_t)b * 256 + ib * 2 + 1) * 512 + (size_t)lane * 8;
        qf0 = *(const f16x8*)(q_hi + qo0);
        qf1 = *(const f16x8*)(q_hi + qo1);
    }

    const s16x8 ones = { (short)0x3F80, (short)0x3F80, (short)0x3F80, (short)0x3F80,
                         (short)0x3F80, (short)0x3F80, (short)0x3F80, (short)0x3F80 };

    f32x4 acc[8];                             // [ct*2+it], constant indices only
    #pragma unroll
    for (int i = 0; i < 8; ++i) acc[i] = (f32x4){0.f, 0.f, 0.f, 0.f};
    f32x4 lacc = {0.f, 0.f, 0.f, 0.f};

    const unsigned short* khb = k_hi + (size_t)b * 131072 + (size_t)lane * 8;
    const unsigned short* vb  = v_frag + (size_t)b * 1048576 + (size_t)lane * 8;

    const int prow = ((ch & 1) << 1) + (quad >> 1);
    const int pcol = ((quad & 1) << 2);
    const int pfrag_jj = ch >> 1;

    // ---- prologue: K(0) -> QK(0) -> P(0) in buf0; prefetch K(1) ----
    f16x8 ka, kb;
    {
        const size_t k0 = (size_t)((jh * 32 + 0) * 4 + ch) * 512;
        ka = *(const f16x8*)(khb + k0);
    }
    QK_STEP(ka, 0);
    {
        const size_t k1 = (size_t)((jh * 32 + 1) * 4 + ch) * 512;
        ka = *(const f16x8*)(khb + k1);
    }
    BARRIER_LGKM();

    #pragma unroll 1
    for (int t2 = 0; t2 < 16; ++t2) {
        ATTN_BODY(2 * t2,     0, ka, kb, 1);
        ATTN_BODY(2 * t2 + 1, 1, kb, ka, (t2 < 15));
    }

    // ---- epilogue (constant indices inside wave-uniform branches) ----
    if (ch < 2 && lane < 16) lds_l[jh][ch][lane] = lacc[0];
    if (jh == 0) {          // own it0; publish it1
        #pragma unroll
        for (int ct = 0; ct < 4; ++ct)
            comb[0][ch][ct][lane] = acc[ct * 2 + 1];
    } else {                // own it1; publish it0
        #pragma unroll
        for (int ct = 0; ct < 4; ++ct)
            comb[1][ch][ct][lane] = acc[ct * 2 + 0];
    }
    __syncthreads();
    const float linv = 1.f / (lds_l[0][jh][l15] + lds_l[1][jh][l15]);
    const int ibase = (ib * 2 + jh) * 16 + l15;
    #pragma unroll
    for (int ct = 0; ct < 4; ++ct) {
        f32x4 a;
        if (jh == 0) a = acc[ct * 2 + 0];
        else         a = acc[ct * 2 + 1];
        a += comb[1 - jh][ch][ct][lane];
        #pragma unroll
        for (int rr = 0; rr < 4; ++rr) {
            const int c = ch * 64 + ct * 16 + quad * 4 + rr;
            const size_t idx = ((size_t)b * CCH + c) * NPIX + ibase;
            out[idx] = a[rr] * linv + x[idx];
        }
    }
}

extern "C" void kernel_launch(void* const* d_in, const int* in_sizes, int n_in,
                              void* d_out, int out_size, void* d_ws, size_t ws_size,
                              hipStream_t stream) {
    const float* x  = (const float*)d_in[0];
    const float* Wq = (const float*)d_in[1];
    const float* bq = (const float*)d_in[2];
    const float* Wk = (const float*)d_in[3];
    const float* bk = (const float*)d_in[4];
    const float* Wv = (const float*)d_in[5];
    const float* bv = (const float*)d_in[6];
    float* out = (float*)d_out;

    unsigned short* ws = (unsigned short*)d_ws;
    unsigned short* q_hi   = ws;                 //   524,288 (fp16)
    unsigned short* k_hi   = ws + 1048576;       //   524,288 (fp16)
    unsigned short* v_frag = ws + 2097152;       // 4,194,304 (bf16)
    unsigned short* wfh    = ws + 6291456;       //    81,920 (fp16)
    unsigned short* wfl    = ws + 6373376;       //    16,384 (fp16)
    float*          bias_ws = (float*)(ws + 6389760);  // 320 floats

    wcast_kernel<<<20, 64, 0, stream>>>(Wq, bq, Wk, bk, Wv, bv, wfh, wfl, bias_ws);
    proj_kernel<<<dim3(256, BATCH), 256, 0, stream>>>(x, wfh, wfl, bias_ws,
                                                      q_hi, k_hi, v_frag);
    attn_kernel<<<512, 512, 0, stream>>>(q_hi, k_hi, v_frag, x, out);
}